// Round 13
// baseline (175.565 us; speedup 1.0000x reference)
//
#include <hip/hip_runtime.h>
#include <hip/hip_bf16.h>
#include <math.h>

typedef __bf16 bf16;
typedef __attribute__((ext_vector_type(8))) __bf16 bf16x8;
typedef __attribute__((ext_vector_type(4))) short s16x4;
typedef __attribute__((ext_vector_type(4))) float f32x4;

#define EMB 768
#define T_SEQ 1024
#define HEADS 12
#define HDIM 64

// ---------------- fused prep: x fp32->bf16, W_attn / W_proj transpose+cvt ----------------
// NOTE (R9-R11 lesson): fusing the x-conversion into gemm1 forces reg-staged A,
// which costs 10-21us vs global_load_lds (catalog m249/m151 confirmed on-device;
// compiler sinks "issue-early" prefetch loads, VGPR stayed 76). Keep the pass.
__global__ void prep_k(const float* __restrict__ x, bf16* __restrict__ xb,
                       const float* __restrict__ Wa, bf16* __restrict__ Wta,
                       const float* __restrict__ Wp, bf16* __restrict__ Wtp) {
  __shared__ float tile[32][33];
  const int blk = blockIdx.x, tid = threadIdx.x;
  if (blk < 3072) {
    const size_t i = (size_t)blk * 256 + tid;
    const float4* p = (const float4*)(x + i * 8);
    const float4 a = p[0], b = p[1];
    bf16x8 v;
    v[0] = (bf16)a.x; v[1] = (bf16)a.y; v[2] = (bf16)a.z; v[3] = (bf16)a.w;
    v[4] = (bf16)b.x; v[5] = (bf16)b.y; v[6] = (bf16)b.z; v[7] = (bf16)b.w;
    *(bf16x8*)(xb + i * 8) = v;
    return;
  }
  const float* in;
  bf16* out;
  int C, t;
  if (blk < 3072 + 1728) { in = Wa; out = Wta; C = 3 * EMB; t = blk - 3072; }
  else                   { in = Wp; out = Wtp; C = EMB;     t = blk - 4800; }
  const int R = EMB;
  const int c0 = (t % (C / 32)) * 32, r0 = (t / (C / 32)) * 32;
  const int tx = tid & 31, ty = tid >> 5;
  for (int i = ty; i < 32; i += 8)
    tile[i][tx] = in[(size_t)(r0 + i) * C + c0 + tx];
  __syncthreads();
  for (int i = ty; i < 32; i += 8)
    out[(size_t)(c0 + i) * R + r0 + tx] = (bf16)tile[tx][i];
}

// ---------------- GEMM: C[M][N] = A[M][K] @ Bt[N][K]^T + bias, BK=64 (2x32) ----------------
// LDS XOR swizzle (verified, bank conflicts = 0): LDS[row][c8] = G[row][c8^((row>>1)&3)]
//  - staging: permute GLOBAL source octet skk, LDS dest linear (rule #21)
//  - read: octet rq = (quad ^ ((lane>>1)&3))*8
// Both A and B staged via global_load_lds (fastest measured path: 41.5us -> best).
template <int MODE, int NXT>
__global__ __launch_bounds__(256) void gemm_bt(
    const bf16* __restrict__ A, const bf16* __restrict__ Bt, const float* __restrict__ bias,
    bf16* __restrict__ Cb, float* __restrict__ Cf, int M, int N, int K) {
  __shared__ __align__(16) bf16 As0[128 * 32];
  __shared__ __align__(16) bf16 As1[128 * 32];
  __shared__ __align__(16) bf16 Bs0[128 * 32];
  __shared__ __align__(16) bf16 Bs1[128 * 32];
  const int lane = threadIdx.x & 63;
  const int wave = threadIdx.x >> 6;
  const int quad = lane >> 4, lc = lane & 15;

  // XCD-aware tile assignment (dispatch round-robins blockIdx % 8 across XCDs)
  const int xcd = blockIdx.x & 7;
  const int idx = blockIdx.x >> 3;           // 0 .. NXT*8-1 per XCD
  const int m0 = (xcd * 8 + (idx & 7)) * 128;
  const int n0 = (idx >> 3) * 128;           // x-outer: W-tile streams, A-tiles persist

  const int wm = (wave >> 1) * 64, wn = (wave & 1) * 64;
  const int srow = lane >> 2;
  const int skk = (((lane & 3) ^ ((lane >> 3) & 3))) * 8;   // swizzled source octet
  const int rq = (quad ^ ((lane >> 1) & 3)) * 8;            // swizzled read octet

  f32x4 zero = {0.f, 0.f, 0.f, 0.f};
  f32x4 acc[4][4];
#pragma unroll
  for (int i = 0; i < 4; ++i)
#pragma unroll
    for (int j = 0; j < 4; ++j) acc[i][j] = zero;

  for (int k0 = 0; k0 < K; k0 += 64) {
    __syncthreads();
#pragma unroll
    for (int c = wave; c < 8; c += 4) {
      const bf16* gA = A + (size_t)(m0 + c * 16 + srow) * K + k0 + skk;
      const bf16* gB = Bt + (size_t)(n0 + c * 16 + srow) * K + k0 + skk;
      __builtin_amdgcn_global_load_lds((const __attribute__((address_space(1))) void*)gA,
                                       (__attribute__((address_space(3))) void*)(As0 + c * 512), 16, 0, 0);
      __builtin_amdgcn_global_load_lds((const __attribute__((address_space(1))) void*)(gA + 32),
                                       (__attribute__((address_space(3))) void*)(As1 + c * 512), 16, 0, 0);
      __builtin_amdgcn_global_load_lds((const __attribute__((address_space(1))) void*)gB,
                                       (__attribute__((address_space(3))) void*)(Bs0 + c * 512), 16, 0, 0);
      __builtin_amdgcn_global_load_lds((const __attribute__((address_space(1))) void*)(gB + 32),
                                       (__attribute__((address_space(3))) void*)(Bs1 + c * 512), 16, 0, 0);
    }
    __syncthreads();
    {
      bf16x8 af[4], bfr[4];
#pragma unroll
      for (int t = 0; t < 4; ++t) af[t] = *(const bf16x8*)&As0[(wm + t * 16 + lc) * 32 + rq];
#pragma unroll
      for (int t = 0; t < 4; ++t) bfr[t] = *(const bf16x8*)&Bs0[(wn + t * 16 + lc) * 32 + rq];
#pragma unroll
      for (int tm = 0; tm < 4; ++tm)
#pragma unroll
        for (int tn = 0; tn < 4; ++tn)
          acc[tm][tn] = __builtin_amdgcn_mfma_f32_16x16x32_bf16(af[tm], bfr[tn], acc[tm][tn], 0, 0, 0);
    }
    {
      bf16x8 af[4], bfr[4];
#pragma unroll
      for (int t = 0; t < 4; ++t) af[t] = *(const bf16x8*)&As1[(wm + t * 16 + lc) * 32 + rq];
#pragma unroll
      for (int t = 0; t < 4; ++t) bfr[t] = *(const bf16x8*)&Bs1[(wn + t * 16 + lc) * 32 + rq];
#pragma unroll
      for (int tm = 0; tm < 4; ++tm)
#pragma unroll
        for (int tn = 0; tn < 4; ++tn)
          acc[tm][tn] = __builtin_amdgcn_mfma_f32_16x16x32_bf16(af[tm], bfr[tn], acc[tm][tn], 0, 0, 0);
    }
  }

#pragma unroll
  for (int tm = 0; tm < 4; ++tm) {
#pragma unroll
    for (int tn = 0; tn < 4; ++tn) {
      const int col = n0 + wn + tn * 16 + lc;
      const float bv = bias[col];
#pragma unroll
      for (int r = 0; r < 4; ++r) {
        const int row = m0 + wm + tm * 16 + quad * 4 + r;
        const float v = acc[tm][tn][r] + bv;
        if (MODE == 0) Cb[(size_t)row * N + col] = (bf16)v;
        else           Cf[(size_t)row * N + col] = v;
      }
    }
  }
}

// ---------------- causal flash attention (R4 variant, best measured) ----------------
// qkv: [B*T][2304] rows (q|k|v); outb: [B*T][768]
//  - T14 async K/V register prefetch; __launch_bounds__(512,2) -> no spills.
//  - V transpose-staging bank-spread: key = 16w + (l>>2), d8 = (l&3)*8 + 32t.
//  - Q in registers (scaled at load); epilogue stages O through Ks.
__global__ __launch_bounds__(512, 2) void attn_k(const bf16* __restrict__ qkv,
                                                 bf16* __restrict__ outb) {
  __shared__ __align__(16) bf16 Ks[128][72];   // [key][d]; reused for O out
  __shared__ __align__(16) bf16 Vt[64][132];   // V^T [d][key]

  const int lane = threadIdx.x & 63;
  const int wave = threadIdx.x >> 6;           // 0..7, each owns 16 q rows
  const int quad = lane >> 4, lc = lane & 15;
  const int flat = blockIdx.x;
  const int bh = flat % (HEADS * 8);
  const int qt = 7 - flat / (HEADS * 8);
  const int h = bh % HEADS;
  const int b = bh / HEADS;
  const int q0 = qt * 128;
  const size_t rowB = (size_t)b * T_SEQ;
  const int hoff = h * HDIM;
  const int tid = threadIdx.x;
  const float C1 = 0.125f * 1.44269504f;       // 1/sqrt(64) * log2(e), folded into Q

  // staging coordinates
  const int kkey0 = tid >> 3;                  // K: key for t=0 chunk (+64 for t=1)
  const int ksd8 = (tid & 7) * 8;              // K: d offset
  const int vkey = wave * 16 + (lane >> 2);    // V: bank-spread mapping
  const int vd8base = (lane & 3) * 8;          // V: d base (+32 for t=1)
  const bf16* kbase = qkv + rowB * (size_t)(3 * EMB) + EMB + hoff;
  const bf16* vbase = qkv + rowB * (size_t)(3 * EMB) + 2 * EMB + hoff;

  // prefetch registers for K/V tile kt=0
  bf16x8 kreg[2], vreg[2];
#pragma unroll
  for (int t = 0; t < 2; ++t) {
    kreg[t] = *(const bf16x8*)(kbase + (size_t)(kkey0 + t * 64) * (3 * EMB) + ksd8);
    vreg[t] = *(const bf16x8*)(vbase + (size_t)vkey * (3 * EMB) + vd8base + t * 32);
  }

  // Q fragments straight to registers (loads overlap the K/V prefetch above)
  bf16x8 qfrag[2];
  {
    const bf16* qrow =
        qkv + (rowB + q0 + wave * 16 + lc) * (size_t)(3 * EMB) + hoff + quad * 8;
#pragma unroll
    for (int ks = 0; ks < 2; ++ks) {
      bf16x8 v = *(const bf16x8*)(qrow + ks * 32);
#pragma unroll
      for (int i = 0; i < 8; ++i) v[i] = (bf16)((float)v[i] * C1);
      qfrag[ks] = v;
    }
  }

  f32x4 zero = {0.f, 0.f, 0.f, 0.f};
  float l_run = 0.f;
  f32x4 o[4];  // O'[d][q]: col q=lc, row d=dt*16+quad*4+r
#pragma unroll
  for (int dt = 0; dt < 4; ++dt) o[dt] = zero;
  const int myq = q0 + wave * 16 + lc;

  for (int kt = 0; kt <= qt; ++kt) {
    const int kb = kt * 128;
    __syncthreads();
    // write prefetched K/V regs into LDS
#pragma unroll
    for (int t = 0; t < 2; ++t)
      *(bf16x8*)&Ks[kkey0 + t * 64][ksd8] = kreg[t];
#pragma unroll
    for (int t = 0; t < 2; ++t) {
      const int d8 = vd8base + t * 32;
#pragma unroll
      for (int i = 0; i < 8; ++i) Vt[d8 + i][vkey] = vreg[t][i];
    }
    __syncthreads();

    // issue next tile's global loads; they retire under this tile's compute
    if (kt < qt) {
      const size_t nb = (size_t)(kt + 1) * 128;
#pragma unroll
      for (int t = 0; t < 2; ++t) {
        kreg[t] = *(const bf16x8*)(kbase + (nb + kkey0 + t * 64) * (3 * EMB) + ksd8);
        vreg[t] = *(const bf16x8*)(vbase + (nb + vkey) * (3 * EMB) + vd8base + t * 32);
      }
    }

    f32x4 s[8];
#pragma unroll
    for (int j = 0; j < 8; ++j) s[j] = zero;
#pragma unroll
    for (int ks = 0; ks < 2; ++ks) {
      bf16x8 bq = qfrag[ks];
#pragma unroll
      for (int j = 0; j < 8; ++j) {
        bf16x8 ak = *(const bf16x8*)&Ks[j * 16 + lc][ks * 32 + quad * 8];
        s[j] = __builtin_amdgcn_mfma_f32_16x16x32_bf16(ak, bq, s[j], 0, 0, 0);
      }
    }

    s16x4 pf[8];
    const bool diag = (kt == qt);
    if (diag) {
#pragma unroll
      for (int j = 0; j < 8; ++j) {
#pragma unroll
        for (int r = 0; r < 4; ++r) {
          const bool masked = (kb + j * 16 + quad * 4 + r > myq);
          const float p = masked ? 0.f : exp2f(s[j][r]);
          l_run += p;
          pf[j][r] = __builtin_bit_cast(short, (bf16)p);
        }
      }
    } else {
#pragma unroll
      for (int j = 0; j < 8; ++j) {
#pragma unroll
        for (int r = 0; r < 4; ++r) {
          const float p = exp2f(s[j][r]);
          l_run += p;
          pf[j][r] = __builtin_bit_cast(short, (bf16)p);
        }
      }
    }

#pragma unroll
    for (int j = 0; j < 8; ++j) {
#pragma unroll
      for (int dt = 0; dt < 4; ++dt) {
        s16x4 av = *(const s16x4*)&Vt[dt * 16 + lc][j * 16 + quad * 4];
        o[dt] = __builtin_amdgcn_mfma_f32_16x16x16bf16_1k(av, pf[j], o[dt], 0, 0, 0);
      }
    }
  }

  l_run += __shfl_xor(l_run, 16);
  l_run += __shfl_xor(l_run, 32);
  const float inv = 1.0f / l_run;
  __syncthreads();
#pragma unroll
  for (int dt = 0; dt < 4; ++dt)
#pragma unroll
    for (int r = 0; r < 4; ++r)
      Ks[wave * 16 + lc][dt * 16 + quad * 4 + r] = (bf16)(o[dt][r] * inv);
  __syncthreads();
  for (int c = tid; c < 128 * 8; c += 512) {
    const int r = c >> 3, d8 = (c & 7) * 8;
    *(bf16x8*)(outb + (rowB + q0 + r) * EMB + hoff + d8) = *(const bf16x8*)&Ks[r][d8];
  }
}

// ---------------- launch ----------------
extern "C" void kernel_launch(void* const* d_in, const int* in_sizes, int n_in,
                              void* d_out, int out_size, void* d_ws, size_t ws_size,
                              hipStream_t stream) {
  const float* x = (const float*)d_in[0];
  const float* Wattn = (const float*)d_in[1];
  const float* battn = (const float*)d_in[2];
  const float* Wproj = (const float*)d_in[3];
  const float* bproj = (const float*)d_in[4];
  float* out = (float*)d_out;

  const int M = in_sizes[0] / EMB;  // 8192
  const int Bn = M / T_SEQ;         // 8

  bf16* ws = (bf16*)d_ws;
  bf16* xb = ws;                                        // [M][768]
  bf16* Wt_attn = xb + (size_t)M * EMB;                 // [2304][768]
  bf16* Wt_proj = Wt_attn + (size_t)3 * EMB * EMB;      // [768][768]
  bf16* qkv = Wt_proj + (size_t)EMB * EMB;              // [M][2304]
  bf16* attnb = qkv + (size_t)M * 3 * EMB;              // [M][768]

  const int cvt_blocks = M * EMB / 8 / 256;             // 3072
  prep_k<<<cvt_blocks + 1728 + 576, 256, 0, stream>>>(x, xb, Wattn, Wt_attn, Wproj, Wt_proj);

  gemm_bt<0, 18><<<18 * 64, 256, 0, stream>>>(
      xb, Wt_attn, battn, qkv, nullptr, M, 3 * EMB, EMB);

  attn_k<<<dim3((T_SEQ / 128) * Bn * HEADS), 512, 0, stream>>>(qkv, attnb);

  gemm_bt<1, 6><<<6 * 64, 256, 0, stream>>>(
      attnb, Wt_proj, bproj, nullptr, out, M, EMB, EMB);
}

// Round 14
// 169.937 us; speedup vs baseline: 1.0331x; 1.0331x over previous
//
#include <hip/hip_runtime.h>
#include <hip/hip_bf16.h>
#include <math.h>

typedef __bf16 bf16;
typedef __attribute__((ext_vector_type(8))) __bf16 bf16x8;
typedef __attribute__((ext_vector_type(4))) short s16x4;
typedef __attribute__((ext_vector_type(4))) float f32x4;

#define EMB 768
#define T_SEQ 1024
#define HEADS 12
#define HDIM 64

// ---------------- fused prep: x fp32->bf16, W_attn / W_proj transpose+cvt ----------------
// NOTE (R9-R11 lesson): fusing the x-conversion into gemm1 forces reg-staged A,
// which costs 10-21us vs global_load_lds. Keep the pass.
__global__ void prep_k(const float* __restrict__ x, bf16* __restrict__ xb,
                       const float* __restrict__ Wa, bf16* __restrict__ Wta,
                       const float* __restrict__ Wp, bf16* __restrict__ Wtp) {
  __shared__ float tile[32][33];
  const int blk = blockIdx.x, tid = threadIdx.x;
  if (blk < 3072) {
    const size_t i = (size_t)blk * 256 + tid;
    const float4* p = (const float4*)(x + i * 8);
    const float4 a = p[0], b = p[1];
    bf16x8 v;
    v[0] = (bf16)a.x; v[1] = (bf16)a.y; v[2] = (bf16)a.z; v[3] = (bf16)a.w;
    v[4] = (bf16)b.x; v[5] = (bf16)b.y; v[6] = (bf16)b.z; v[7] = (bf16)b.w;
    *(bf16x8*)(xb + i * 8) = v;
    return;
  }
  const float* in;
  bf16* out;
  int C, t;
  if (blk < 3072 + 1728) { in = Wa; out = Wta; C = 3 * EMB; t = blk - 3072; }
  else                   { in = Wp; out = Wtp; C = EMB;     t = blk - 4800; }
  const int R = EMB;
  const int c0 = (t % (C / 32)) * 32, r0 = (t / (C / 32)) * 32;
  const int tx = tid & 31, ty = tid >> 5;
  for (int i = ty; i < 32; i += 8)
    tile[i][tx] = in[(size_t)(r0 + i) * C + c0 + tx];
  __syncthreads();
  for (int i = ty; i < 32; i += 8)
    out[(size_t)(c0 + i) * R + r0 + tx] = (bf16)tile[tx][i];
}

// ---------------- GEMM: C[M][N] = A[M][K] @ Bt[N][K]^T + bias, BK=64 (2x32) ----------------
// LDS XOR swizzle (verified, bank conflicts = 0): LDS[row][c8] = G[row][c8^((row>>1)&3)]
//  - staging: permute GLOBAL source octet skk, LDS dest linear (rule #21)
//  - read: octet rq = (quad ^ ((lane>>1)&3))*8
// Both A and B staged via global_load_lds (fastest measured path).
template <int MODE, int NXT>
__global__ __launch_bounds__(256) void gemm_bt(
    const bf16* __restrict__ A, const bf16* __restrict__ Bt, const float* __restrict__ bias,
    bf16* __restrict__ Cb, float* __restrict__ Cf, int M, int N, int K) {
  __shared__ __align__(16) bf16 As0[128 * 32];
  __shared__ __align__(16) bf16 As1[128 * 32];
  __shared__ __align__(16) bf16 Bs0[128 * 32];
  __shared__ __align__(16) bf16 Bs1[128 * 32];
  const int lane = threadIdx.x & 63;
  const int wave = threadIdx.x >> 6;
  const int quad = lane >> 4, lc = lane & 15;

  // XCD-aware tile assignment (dispatch round-robins blockIdx % 8 across XCDs)
  const int xcd = blockIdx.x & 7;
  const int idx = blockIdx.x >> 3;           // 0 .. NXT*8-1 per XCD
  const int m0 = (xcd * 8 + (idx & 7)) * 128;
  const int n0 = (idx >> 3) * 128;           // x-outer: W-tile streams, A-tiles persist

  const int wm = (wave >> 1) * 64, wn = (wave & 1) * 64;
  const int srow = lane >> 2;
  const int skk = (((lane & 3) ^ ((lane >> 3) & 3))) * 8;   // swizzled source octet
  const int rq = (quad ^ ((lane >> 1) & 3)) * 8;            // swizzled read octet

  f32x4 zero = {0.f, 0.f, 0.f, 0.f};
  f32x4 acc[4][4];
#pragma unroll
  for (int i = 0; i < 4; ++i)
#pragma unroll
    for (int j = 0; j < 4; ++j) acc[i][j] = zero;

  for (int k0 = 0; k0 < K; k0 += 64) {
    __syncthreads();
#pragma unroll
    for (int c = wave; c < 8; c += 4) {
      const bf16* gA = A + (size_t)(m0 + c * 16 + srow) * K + k0 + skk;
      const bf16* gB = Bt + (size_t)(n0 + c * 16 + srow) * K + k0 + skk;
      __builtin_amdgcn_global_load_lds((const __attribute__((address_space(1))) void*)gA,
                                       (__attribute__((address_space(3))) void*)(As0 + c * 512), 16, 0, 0);
      __builtin_amdgcn_global_load_lds((const __attribute__((address_space(1))) void*)(gA + 32),
                                       (__attribute__((address_space(3))) void*)(As1 + c * 512), 16, 0, 0);
      __builtin_amdgcn_global_load_lds((const __attribute__((address_space(1))) void*)gB,
                                       (__attribute__((address_space(3))) void*)(Bs0 + c * 512), 16, 0, 0);
      __builtin_amdgcn_global_load_lds((const __attribute__((address_space(1))) void*)(gB + 32),
                                       (__attribute__((address_space(3))) void*)(Bs1 + c * 512), 16, 0, 0);
    }
    __syncthreads();
    {
      bf16x8 af[4], bfr[4];
#pragma unroll
      for (int t = 0; t < 4; ++t) af[t] = *(const bf16x8*)&As0[(wm + t * 16 + lc) * 32 + rq];
#pragma unroll
      for (int t = 0; t < 4; ++t) bfr[t] = *(const bf16x8*)&Bs0[(wn + t * 16 + lc) * 32 + rq];
#pragma unroll
      for (int tm = 0; tm < 4; ++tm)
#pragma unroll
        for (int tn = 0; tn < 4; ++tn)
          acc[tm][tn] = __builtin_amdgcn_mfma_f32_16x16x32_bf16(af[tm], bfr[tn], acc[tm][tn], 0, 0, 0);
    }
    {
      bf16x8 af[4], bfr[4];
#pragma unroll
      for (int t = 0; t < 4; ++t) af[t] = *(const bf16x8*)&As1[(wm + t * 16 + lc) * 32 + rq];
#pragma unroll
      for (int t = 0; t < 4; ++t) bfr[t] = *(const bf16x8*)&Bs1[(wn + t * 16 + lc) * 32 + rq];
#pragma unroll
      for (int tm = 0; tm < 4; ++tm)
#pragma unroll
        for (int tn = 0; tn < 4; ++tn)
          acc[tm][tn] = __builtin_amdgcn_mfma_f32_16x16x32_bf16(af[tm], bfr[tn], acc[tm][tn], 0, 0, 0);
    }
  }

#pragma unroll
  for (int tm = 0; tm < 4; ++tm) {
#pragma unroll
    for (int tn = 0; tn < 4; ++tn) {
      const int col = n0 + wn + tn * 16 + lc;
      const float bv = bias[col];
#pragma unroll
      for (int r = 0; r < 4; ++r) {
        const int row = m0 + wm + tm * 16 + quad * 4 + r;
        const float v = acc[tm][tn][r] + bv;
        if (MODE == 0) Cb[(size_t)row * N + col] = (bf16)v;
        else           Cf[(size_t)row * N + col] = v;
      }
    }
  }
}

// ---------------- causal flash attention ----------------
// qkv: [B*T][2304] rows (q|k|v); outb: [B*T][768]
// R13: softmax denominator via MFMA ones-trick. l_run was 64 ORDER-PINNED fp32
// adds/tile/lane (no fast-math -> serial dep chain ~256cy) + 2 shfl_xor.
// Replaced by ol = mfma(ones, pf[j], ol): ol[r] = sum_k P[k][q=lc] — complete l
// for this lane's own q (pf B-operand cols = the wave's 16 q rows, col=lc; all
// 4 r-slots equal; masked p=0 contributes 0; diagonal always unmasked -> l>0).
// l now sums bf16-rounded p, CONSISTENT with the O numerator (same rounded p).
//  - T14 async K/V register prefetch; __launch_bounds__(512,2) -> no spills.
//  - V transpose-staging bank-spread: key = 16w + (l>>2), d8 = (l&3)*8 + 32t.
//  - Q in registers (scaled at load); epilogue stages O through Ks.
__global__ __launch_bounds__(512, 2) void attn_k(const bf16* __restrict__ qkv,
                                                 bf16* __restrict__ outb) {
  __shared__ __align__(16) bf16 Ks[128][72];   // [key][d]; reused for O out
  __shared__ __align__(16) bf16 Vt[64][132];   // V^T [d][key]

  const int lane = threadIdx.x & 63;
  const int wave = threadIdx.x >> 6;           // 0..7, each owns 16 q rows
  const int quad = lane >> 4, lc = lane & 15;
  const int flat = blockIdx.x;
  const int bh = flat % (HEADS * 8);
  const int qt = 7 - flat / (HEADS * 8);
  const int h = bh % HEADS;
  const int b = bh / HEADS;
  const int q0 = qt * 128;
  const size_t rowB = (size_t)b * T_SEQ;
  const int hoff = h * HDIM;
  const int tid = threadIdx.x;
  const float C1 = 0.125f * 1.44269504f;       // 1/sqrt(64) * log2(e), folded into Q

  // staging coordinates
  const int kkey0 = tid >> 3;                  // K: key for t=0 chunk (+64 for t=1)
  const int ksd8 = (tid & 7) * 8;              // K: d offset
  const int vkey = wave * 16 + (lane >> 2);    // V: bank-spread mapping
  const int vd8base = (lane & 3) * 8;          // V: d base (+32 for t=1)
  const bf16* kbase = qkv + rowB * (size_t)(3 * EMB) + EMB + hoff;
  const bf16* vbase = qkv + rowB * (size_t)(3 * EMB) + 2 * EMB + hoff;

  // prefetch registers for K/V tile kt=0
  bf16x8 kreg[2], vreg[2];
#pragma unroll
  for (int t = 0; t < 2; ++t) {
    kreg[t] = *(const bf16x8*)(kbase + (size_t)(kkey0 + t * 64) * (3 * EMB) + ksd8);
    vreg[t] = *(const bf16x8*)(vbase + (size_t)vkey * (3 * EMB) + vd8base + t * 32);
  }

  // Q fragments straight to registers (loads overlap the K/V prefetch above)
  bf16x8 qfrag[2];
  {
    const bf16* qrow =
        qkv + (rowB + q0 + wave * 16 + lc) * (size_t)(3 * EMB) + hoff + quad * 8;
#pragma unroll
    for (int ks = 0; ks < 2; ++ks) {
      bf16x8 v = *(const bf16x8*)(qrow + ks * 32);
#pragma unroll
      for (int i = 0; i < 8; ++i) v[i] = (bf16)((float)v[i] * C1);
      qfrag[ks] = v;
    }
  }

  f32x4 zero = {0.f, 0.f, 0.f, 0.f};
  f32x4 o[4];   // O'[d][q]: col q=lc, row d=dt*16+quad*4+r
  f32x4 ol = zero;  // softmax denominator accumulator (ones-trick)
#pragma unroll
  for (int dt = 0; dt < 4; ++dt) o[dt] = zero;
  const int myq = q0 + wave * 16 + lc;

  const short one_bf = (short)0x3F80;          // bf16 1.0
  const s16x4 ones = {one_bf, one_bf, one_bf, one_bf};

  for (int kt = 0; kt <= qt; ++kt) {
    const int kb = kt * 128;
    __syncthreads();
    // write prefetched K/V regs into LDS
#pragma unroll
    for (int t = 0; t < 2; ++t)
      *(bf16x8*)&Ks[kkey0 + t * 64][ksd8] = kreg[t];
#pragma unroll
    for (int t = 0; t < 2; ++t) {
      const int d8 = vd8base + t * 32;
#pragma unroll
      for (int i = 0; i < 8; ++i) Vt[d8 + i][vkey] = vreg[t][i];
    }
    __syncthreads();

    // issue next tile's global loads; they retire under this tile's compute
    if (kt < qt) {
      const size_t nb = (size_t)(kt + 1) * 128;
#pragma unroll
      for (int t = 0; t < 2; ++t) {
        kreg[t] = *(const bf16x8*)(kbase + (nb + kkey0 + t * 64) * (3 * EMB) + ksd8);
        vreg[t] = *(const bf16x8*)(vbase + (nb + vkey) * (3 * EMB) + vd8base + t * 32);
      }
    }

    f32x4 s[8];
#pragma unroll
    for (int j = 0; j < 8; ++j) s[j] = zero;
#pragma unroll
    for (int ks = 0; ks < 2; ++ks) {
      bf16x8 bq = qfrag[ks];
#pragma unroll
      for (int j = 0; j < 8; ++j) {
        bf16x8 ak = *(const bf16x8*)&Ks[j * 16 + lc][ks * 32 + quad * 8];
        s[j] = __builtin_amdgcn_mfma_f32_16x16x32_bf16(ak, bq, s[j], 0, 0, 0);
      }
    }

    s16x4 pf[8];
    const bool diag = (kt == qt);
    if (diag) {
#pragma unroll
      for (int j = 0; j < 8; ++j) {
#pragma unroll
        for (int r = 0; r < 4; ++r) {
          const bool masked = (kb + j * 16 + quad * 4 + r > myq);
          const float p = masked ? 0.f : exp2f(s[j][r]);
          pf[j][r] = __builtin_bit_cast(short, (bf16)p);
        }
      }
    } else {
#pragma unroll
      for (int j = 0; j < 8; ++j) {
#pragma unroll
        for (int r = 0; r < 4; ++r) {
          const float p = exp2f(s[j][r]);
          pf[j][r] = __builtin_bit_cast(short, (bf16)p);
        }
      }
    }

#pragma unroll
    for (int j = 0; j < 8; ++j) {
      ol = __builtin_amdgcn_mfma_f32_16x16x16bf16_1k(ones, pf[j], ol, 0, 0, 0);
#pragma unroll
      for (int dt = 0; dt < 4; ++dt) {
        s16x4 av = *(const s16x4*)&Vt[dt * 16 + lc][j * 16 + quad * 4];
        o[dt] = __builtin_amdgcn_mfma_f32_16x16x16bf16_1k(av, pf[j], o[dt], 0, 0, 0);
      }
    }
  }

  const float inv = 1.0f / ol[0];
  __syncthreads();
#pragma unroll
  for (int dt = 0; dt < 4; ++dt)
#pragma unroll
    for (int r = 0; r < 4; ++r)
      Ks[wave * 16 + lc][dt * 16 + quad * 4 + r] = (bf16)(o[dt][r] * inv);
  __syncthreads();
  for (int c = tid; c < 128 * 8; c += 512) {
    const int r = c >> 3, d8 = (c & 7) * 8;
    *(bf16x8*)(outb + (rowB + q0 + r) * EMB + hoff + d8) = *(const bf16x8*)&Ks[r][d8];
  }
}

// ---------------- launch ----------------
extern "C" void kernel_launch(void* const* d_in, const int* in_sizes, int n_in,
                              void* d_out, int out_size, void* d_ws, size_t ws_size,
                              hipStream_t stream) {
  const float* x = (const float*)d_in[0];
  const float* Wattn = (const float*)d_in[1];
  const float* battn = (const float*)d_in[2];
  const float* Wproj = (const float*)d_in[3];
  const float* bproj = (const float*)d_in[4];
  float* out = (float*)d_out;

  const int M = in_sizes[0] / EMB;  // 8192
  const int Bn = M / T_SEQ;         // 8

  bf16* ws = (bf16*)d_ws;
  bf16* xb = ws;                                        // [M][768]
  bf16* Wt_attn = xb + (size_t)M * EMB;                 // [2304][768]
  bf16* Wt_proj = Wt_attn + (size_t)3 * EMB * EMB;      // [768][768]
  bf16* qkv = Wt_proj + (size_t)EMB * EMB;              // [M][2304]
  bf16* attnb = qkv + (size_t)M * 3 * EMB;              // [M][768]

  const int cvt_blocks = M * EMB / 8 / 256;             // 3072
  prep_k<<<cvt_blocks + 1728 + 576, 256, 0, stream>>>(x, xb, Wattn, Wt_attn, Wproj, Wt_proj);

  gemm_bt<0, 18><<<18 * 64, 256, 0, stream>>>(
      xb, Wt_attn, battn, qkv, nullptr, M, 3 * EMB, EMB);

  attn_k<<<dim3((T_SEQ / 128) * Bn * HEADS), 512, 0, stream>>>(qkv, attnb);

  gemm_bt<1, 6><<<6 * 64, 256, 0, stream>>>(
      attnb, Wt_proj, bproj, nullptr, out, M, EMB, EMB);
}

// Round 16
// 169.127 us; speedup vs baseline: 1.0381x; 1.0048x over previous
//
#include <hip/hip_runtime.h>
#include <hip/hip_bf16.h>
#include <math.h>

typedef __bf16 bf16;
typedef __attribute__((ext_vector_type(8))) __bf16 bf16x8;
typedef __attribute__((ext_vector_type(4))) short s16x4;
typedef __attribute__((ext_vector_type(4))) float f32x4;

#define EMB 768
#define T_SEQ 1024
#define HEADS 12
#define HDIM 64

// ---------------- fused prep: x fp32->bf16, W_attn / W_proj transpose+cvt ----------------
// NOTE (R9-R11 lesson): fusing the x-conversion into gemm1 forces reg-staged A,
// which costs 10-21us vs global_load_lds. Keep the pass.
__global__ void prep_k(const float* __restrict__ x, bf16* __restrict__ xb,
                       const float* __restrict__ Wa, bf16* __restrict__ Wta,
                       const float* __restrict__ Wp, bf16* __restrict__ Wtp) {
  __shared__ float tile[32][33];
  const int blk = blockIdx.x, tid = threadIdx.x;
  if (blk < 3072) {
    const size_t i = (size_t)blk * 256 + tid;
    const float4* p = (const float4*)(x + i * 8);
    const float4 a = p[0], b = p[1];
    bf16x8 v;
    v[0] = (bf16)a.x; v[1] = (bf16)a.y; v[2] = (bf16)a.z; v[3] = (bf16)a.w;
    v[4] = (bf16)b.x; v[5] = (bf16)b.y; v[6] = (bf16)b.z; v[7] = (bf16)b.w;
    *(bf16x8*)(xb + i * 8) = v;
    return;
  }
  const float* in;
  bf16* out;
  int C, t;
  if (blk < 3072 + 1728) { in = Wa; out = Wta; C = 3 * EMB; t = blk - 3072; }
  else                   { in = Wp; out = Wtp; C = EMB;     t = blk - 4800; }
  const int R = EMB;
  const int c0 = (t % (C / 32)) * 32, r0 = (t / (C / 32)) * 32;
  const int tx = tid & 31, ty = tid >> 5;
  for (int i = ty; i < 32; i += 8)
    tile[i][tx] = in[(size_t)(r0 + i) * C + c0 + tx];
  __syncthreads();
  for (int i = ty; i < 32; i += 8)
    out[(size_t)(c0 + i) * R + r0 + tx] = (bf16)tile[tx][i];
}

// ---------------- GEMM: C[M][N] = A[M][K] @ Bt[N][K]^T + bias, BK=64 (2x32) ----------------
// LDS XOR swizzle (verified, bank conflicts = 0): LDS[row][c8] = G[row][c8^((row>>1)&3)]
//  - staging: permute GLOBAL source octet skk, LDS dest linear (rule #21)
//  - read: octet rq = (quad ^ ((lane>>1)&3))*8
// Both A and B staged via global_load_lds (fastest measured path).
// R14: BN template param. BN=128: 2Mx2N waves, 64-row wave tiles (as before).
// BN=64 (gemm2): 128x64 tiles -> grid 64x12=768 blocks = 3 blocks/CU (was 384
// = 1.5 blocks/CU, half the CUs idle in the tail). Waves 4Mx1N: wm=wave*32,
// MT=2 m-frags, acc[2][4]. Swizzle algebra invariant: store (row>>1)&3 =
// (lane>>3)&3 (chunk base c*16 = 0 mod 8), read (row>>1)&3 = (lc>>1)&3.
template <int MODE, int NXT, int BN>
__global__ __launch_bounds__(256) void gemm_bt(
    const bf16* __restrict__ A, const bf16* __restrict__ Bt, const float* __restrict__ bias,
    bf16* __restrict__ Cb, float* __restrict__ Cf, int M, int N, int K) {
  constexpr int MT = (BN == 128) ? 4 : 2;    // m-frags per wave
  constexpr int NWN = (BN == 128) ? 2 : 1;   // waves in N
  __shared__ __align__(16) bf16 As0[128 * 32];
  __shared__ __align__(16) bf16 As1[128 * 32];
  __shared__ __align__(16) bf16 Bs0[BN * 32];
  __shared__ __align__(16) bf16 Bs1[BN * 32];
  const int lane = threadIdx.x & 63;
  const int wave = threadIdx.x >> 6;
  const int quad = lane >> 4, lc = lane & 15;

  // XCD-aware tile assignment (dispatch round-robins blockIdx % 8 across XCDs)
  const int xcd = blockIdx.x & 7;
  const int idx = blockIdx.x >> 3;           // 0 .. NXT*8-1 per XCD
  const int m0 = (xcd * 8 + (idx & 7)) * 128;
  const int n0 = (idx >> 3) * BN;            // x-outer: W-tile streams, A-tiles persist

  const int wm = (wave / NWN) * (MT * 16);
  const int wn = (wave % NWN) * 64;
  const int srow = lane >> 2;
  const int skk = (((lane & 3) ^ ((lane >> 3) & 3))) * 8;   // swizzled source octet
  const int rq = (quad ^ ((lane >> 1) & 3)) * 8;            // swizzled read octet

  f32x4 zero = {0.f, 0.f, 0.f, 0.f};
  f32x4 acc[MT][4];
#pragma unroll
  for (int i = 0; i < MT; ++i)
#pragma unroll
    for (int j = 0; j < 4; ++j) acc[i][j] = zero;

  for (int k0 = 0; k0 < K; k0 += 64) {
    __syncthreads();
#pragma unroll
    for (int c = wave; c < 8; c += 4) {
      const bf16* gA = A + (size_t)(m0 + c * 16 + srow) * K + k0 + skk;
      __builtin_amdgcn_global_load_lds((const __attribute__((address_space(1))) void*)gA,
                                       (__attribute__((address_space(3))) void*)(As0 + c * 512), 16, 0, 0);
      __builtin_amdgcn_global_load_lds((const __attribute__((address_space(1))) void*)(gA + 32),
                                       (__attribute__((address_space(3))) void*)(As1 + c * 512), 16, 0, 0);
    }
#pragma unroll
    for (int c = wave; c < BN / 16; c += 4) {
      const bf16* gB = Bt + (size_t)(n0 + c * 16 + srow) * K + k0 + skk;
      __builtin_amdgcn_global_load_lds((const __attribute__((address_space(1))) void*)gB,
                                       (__attribute__((address_space(3))) void*)(Bs0 + c * 512), 16, 0, 0);
      __builtin_amdgcn_global_load_lds((const __attribute__((address_space(1))) void*)(gB + 32),
                                       (__attribute__((address_space(3))) void*)(Bs1 + c * 512), 16, 0, 0);
    }
    __syncthreads();
    {
      bf16x8 af[MT], bfr[4];
#pragma unroll
      for (int t = 0; t < MT; ++t) af[t] = *(const bf16x8*)&As0[(wm + t * 16 + lc) * 32 + rq];
#pragma unroll
      for (int t = 0; t < 4; ++t) bfr[t] = *(const bf16x8*)&Bs0[(wn + t * 16 + lc) * 32 + rq];
#pragma unroll
      for (int tm = 0; tm < MT; ++tm)
#pragma unroll
        for (int tn = 0; tn < 4; ++tn)
          acc[tm][tn] = __builtin_amdgcn_mfma_f32_16x16x32_bf16(af[tm], bfr[tn], acc[tm][tn], 0, 0, 0);
    }
    {
      bf16x8 af[MT], bfr[4];
#pragma unroll
      for (int t = 0; t < MT; ++t) af[t] = *(const bf16x8*)&As1[(wm + t * 16 + lc) * 32 + rq];
#pragma unroll
      for (int t = 0; t < 4; ++t) bfr[t] = *(const bf16x8*)&Bs1[(wn + t * 16 + lc) * 32 + rq];
#pragma unroll
      for (int tm = 0; tm < MT; ++tm)
#pragma unroll
        for (int tn = 0; tn < 4; ++tn)
          acc[tm][tn] = __builtin_amdgcn_mfma_f32_16x16x32_bf16(af[tm], bfr[tn], acc[tm][tn], 0, 0, 0);
    }
  }

#pragma unroll
  for (int tm = 0; tm < MT; ++tm) {
#pragma unroll
    for (int tn = 0; tn < 4; ++tn) {
      const int col = n0 + wn + tn * 16 + lc;
      const float bv = bias[col];
#pragma unroll
      for (int r = 0; r < 4; ++r) {
        const int row = m0 + wm + tm * 16 + quad * 4 + r;
        const float v = acc[tm][tn][r] + bv;
        if (MODE == 0) Cb[(size_t)row * N + col] = (bf16)v;
        else           Cf[(size_t)row * N + col] = v;
      }
    }
  }
}

// ---------------- causal flash attention ----------------
// qkv: [B*T][2304] rows (q|k|v); outb: [B*T][768]
// R13: softmax denominator via MFMA ones-trick (verified, -3us):
// ol = mfma(ones, pf[j], ol) -> ol[r] = full l for this lane's q; replaces 64
// order-pinned fp32 adds/tile + 2 shfl_xor. l sums bf16-rounded p, consistent
// with the O numerator.
//  - T14 async K/V register prefetch; __launch_bounds__(512,2) -> no spills.
//  - V transpose-staging bank-spread: key = 16w + (l>>2), d8 = (l&3)*8 + 32t.
//  - Q in registers (scaled at load); epilogue stages O through Ks.
__global__ __launch_bounds__(512, 2) void attn_k(const bf16* __restrict__ qkv,
                                                 bf16* __restrict__ outb) {
  __shared__ __align__(16) bf16 Ks[128][72];   // [key][d]; reused for O out
  __shared__ __align__(16) bf16 Vt[64][132];   // V^T [d][key]

  const int lane = threadIdx.x & 63;
  const int wave = threadIdx.x >> 6;           // 0..7, each owns 16 q rows
  const int quad = lane >> 4, lc = lane & 15;
  const int flat = blockIdx.x;
  const int bh = flat % (HEADS * 8);
  const int qt = 7 - flat / (HEADS * 8);
  const int h = bh % HEADS;
  const int b = bh / HEADS;
  const int q0 = qt * 128;
  const size_t rowB = (size_t)b * T_SEQ;
  const int hoff = h * HDIM;
  const int tid = threadIdx.x;
  const float C1 = 0.125f * 1.44269504f;       // 1/sqrt(64) * log2(e), folded into Q

  // staging coordinates
  const int kkey0 = tid >> 3;                  // K: key for t=0 chunk (+64 for t=1)
  const int ksd8 = (tid & 7) * 8;              // K: d offset
  const int vkey = wave * 16 + (lane >> 2);    // V: bank-spread mapping
  const int vd8base = (lane & 3) * 8;          // V: d base (+32 for t=1)
  const bf16* kbase = qkv + rowB * (size_t)(3 * EMB) + EMB + hoff;
  const bf16* vbase = qkv + rowB * (size_t)(3 * EMB) + 2 * EMB + hoff;

  // prefetch registers for K/V tile kt=0
  bf16x8 kreg[2], vreg[2];
#pragma unroll
  for (int t = 0; t < 2; ++t) {
    kreg[t] = *(const bf16x8*)(kbase + (size_t)(kkey0 + t * 64) * (3 * EMB) + ksd8);
    vreg[t] = *(const bf16x8*)(vbase + (size_t)vkey * (3 * EMB) + vd8base + t * 32);
  }

  // Q fragments straight to registers (loads overlap the K/V prefetch above)
  bf16x8 qfrag[2];
  {
    const bf16* qrow =
        qkv + (rowB + q0 + wave * 16 + lc) * (size_t)(3 * EMB) + hoff + quad * 8;
#pragma unroll
    for (int ks = 0; ks < 2; ++ks) {
      bf16x8 v = *(const bf16x8*)(qrow + ks * 32);
#pragma unroll
      for (int i = 0; i < 8; ++i) v[i] = (bf16)((float)v[i] * C1);
      qfrag[ks] = v;
    }
  }

  f32x4 zero = {0.f, 0.f, 0.f, 0.f};
  f32x4 o[4];   // O'[d][q]: col q=lc, row d=dt*16+quad*4+r
  f32x4 ol = zero;  // softmax denominator accumulator (ones-trick)
#pragma unroll
  for (int dt = 0; dt < 4; ++dt) o[dt] = zero;
  const int myq = q0 + wave * 16 + lc;

  const short one_bf = (short)0x3F80;          // bf16 1.0
  const s16x4 ones = {one_bf, one_bf, one_bf, one_bf};

  for (int kt = 0; kt <= qt; ++kt) {
    const int kb = kt * 128;
    __syncthreads();
    // write prefetched K/V regs into LDS
#pragma unroll
    for (int t = 0; t < 2; ++t)
      *(bf16x8*)&Ks[kkey0 + t * 64][ksd8] = kreg[t];
#pragma unroll
    for (int t = 0; t < 2; ++t) {
      const int d8 = vd8base + t * 32;
#pragma unroll
      for (int i = 0; i < 8; ++i) Vt[d8 + i][vkey] = vreg[t][i];
    }
    __syncthreads();

    // issue next tile's global loads; they retire under this tile's compute
    if (kt < qt) {
      const size_t nb = (size_t)(kt + 1) * 128;
#pragma unroll
      for (int t = 0; t < 2; ++t) {
        kreg[t] = *(const bf16x8*)(kbase + (nb + kkey0 + t * 64) * (3 * EMB) + ksd8);
        vreg[t] = *(const bf16x8*)(vbase + (nb + vkey) * (3 * EMB) + vd8base + t * 32);
      }
    }

    f32x4 s[8];
#pragma unroll
    for (int j = 0; j < 8; ++j) s[j] = zero;
#pragma unroll
    for (int ks = 0; ks < 2; ++ks) {
      bf16x8 bq = qfrag[ks];
#pragma unroll
      for (int j = 0; j < 8; ++j) {
        bf16x8 ak = *(const bf16x8*)&Ks[j * 16 + lc][ks * 32 + quad * 8];
        s[j] = __builtin_amdgcn_mfma_f32_16x16x32_bf16(ak, bq, s[j], 0, 0, 0);
      }
    }

    s16x4 pf[8];
    const bool diag = (kt == qt);
    if (diag) {
#pragma unroll
      for (int j = 0; j < 8; ++j) {
#pragma unroll
        for (int r = 0; r < 4; ++r) {
          const bool masked = (kb + j * 16 + quad * 4 + r > myq);
          const float p = masked ? 0.f : exp2f(s[j][r]);
          pf[j][r] = __builtin_bit_cast(short, (bf16)p);
        }
      }
    } else {
#pragma unroll
      for (int j = 0; j < 8; ++j) {
#pragma unroll
        for (int r = 0; r < 4; ++r) {
          const float p = exp2f(s[j][r]);
          pf[j][r] = __builtin_bit_cast(short, (bf16)p);
        }
      }
    }

#pragma unroll
    for (int j = 0; j < 8; ++j) {
      ol = __builtin_amdgcn_mfma_f32_16x16x16bf16_1k(ones, pf[j], ol, 0, 0, 0);
#pragma unroll
      for (int dt = 0; dt < 4; ++dt) {
        s16x4 av = *(const s16x4*)&Vt[dt * 16 + lc][j * 16 + quad * 4];
        o[dt] = __builtin_amdgcn_mfma_f32_16x16x16bf16_1k(av, pf[j], o[dt], 0, 0, 0);
      }
    }
  }

  const float inv = 1.0f / ol[0];
  __syncthreads();
#pragma unroll
  for (int dt = 0; dt < 4; ++dt)
#pragma unroll
    for (int r = 0; r < 4; ++r)
      Ks[wave * 16 + lc][dt * 16 + quad * 4 + r] = (bf16)(o[dt][r] * inv);
  __syncthreads();
  for (int c = tid; c < 128 * 8; c += 512) {
    const int r = c >> 3, d8 = (c & 7) * 8;
    *(bf16x8*)(outb + (rowB + q0 + r) * EMB + hoff + d8) = *(const bf16x8*)&Ks[r][d8];
  }
}

// ---------------- launch ----------------
extern "C" void kernel_launch(void* const* d_in, const int* in_sizes, int n_in,
                              void* d_out, int out_size, void* d_ws, size_t ws_size,
                              hipStream_t stream) {
  const float* x = (const float*)d_in[0];
  const float* Wattn = (const float*)d_in[1];
  const float* battn = (const float*)d_in[2];
  const float* Wproj = (const float*)d_in[3];
  const float* bproj = (const float*)d_in[4];
  float* out = (float*)d_out;

  const int M = in_sizes[0] / EMB;  // 8192
  const int Bn = M / T_SEQ;         // 8

  bf16* ws = (bf16*)d_ws;
  bf16* xb = ws;                                        // [M][768]
  bf16* Wt_attn = xb + (size_t)M * EMB;                 // [2304][768]
  bf16* Wt_proj = Wt_attn + (size_t)3 * EMB * EMB;      // [768][768]
  bf16* qkv = Wt_proj + (size_t)EMB * EMB;              // [M][2304]
  bf16* attnb = qkv + (size_t)M * 3 * EMB;              // [M][768]

  const int cvt_blocks = M * EMB / 8 / 256;             // 3072
  prep_k<<<cvt_blocks + 1728 + 576, 256, 0, stream>>>(x, xb, Wattn, Wt_attn, Wproj, Wt_proj);

  gemm_bt<0, 18, 128><<<18 * 64, 256, 0, stream>>>(
      xb, Wt_attn, battn, qkv, nullptr, M, 3 * EMB, EMB);

  attn_k<<<dim3((T_SEQ / 128) * Bn * HEADS), 512, 0, stream>>>(qkv, attnb);

  gemm_bt<1, 12, 64><<<12 * 64, 256, 0, stream>>>(
      attnb, Wt_proj, bproj, nullptr, out, M, EMB, EMB);
}